// Round 1
// baseline (440.055 us; speedup 1.0000x reference)
//
#include <hip/hip_runtime.h>

namespace {
constexpr int E_N  = 131072;
constexpr int FEA  = 256;
constexpr int RAD  = 64;
constexpr int HID  = 128;
constexpr int WN   = 256;
constexpr int EPB  = 64;    // edges per block
constexpr int NT   = 256;   // threads per block
}

__global__ __launch_bounds__(NT, 3)
void fused_mlp_dtp(
    const float* __restrict__ fea_a, const float* __restrict__ vec_a,
    const float* __restrict__ len_a, const float* __restrict__ W1_a,
    const float* __restrict__ b1_a,  const float* __restrict__ g_a,
    const float* __restrict__ be_a,  const float* __restrict__ W2_a,
    const float* __restrict__ fea_b, const float* __restrict__ vec_b,
    const float* __restrict__ len_b, const float* __restrict__ W1_b,
    const float* __restrict__ b1_b,  const float* __restrict__ g_b,
    const float* __restrict__ be_b,  const float* __restrict__ W2_b,
    float* __restrict__ out)
{
    __shared__ float sLen[EPB * RAD];   // 16 KB
    __shared__ float sAct[EPB * HID];   // 32 KB  (h, then silu in-place)

    const int pipe = blockIdx.y;
    const float* __restrict__ fea = pipe ? fea_b : fea_a;
    const float* __restrict__ vec = pipe ? vec_b : vec_a;
    const float* __restrict__ len = pipe ? len_b : len_a;
    const float* __restrict__ W1  = pipe ? W1_b  : W1_a;
    const float* __restrict__ b1  = pipe ? b1_b  : b1_a;
    const float* __restrict__ g   = pipe ? g_b   : g_a;
    const float* __restrict__ be  = pipe ? be_b  : be_a;
    const float* __restrict__ W2  = pipe ? W2_b  : W2_a;
    float* __restrict__ outp = out + (size_t)pipe * (size_t)E_N * FEA;

    const int t = threadIdx.x;
    const long e0 = (long)blockIdx.x * EPB;

    // ---------- Phase 1: stage len tile [64][64] ----------
    {
        const float4* __restrict__ src = (const float4*)(len + e0 * RAD);
        float4* dst = (float4*)sLen;
        #pragma unroll
        for (int i = 0; i < (EPB * RAD / 4) / NT; ++i)
            dst[t + i * NT] = src[t + i * NT];
    }
    __syncthreads();

    // ---------- Phase 2: h = len @ W1 + b1  -> sAct ----------
    {
        const int c0 = (t & 31) * 4;        // col block 0..124
        const int eb = (t >> 5) * 8;        // edge block 0..56
        float acc[8][4];
        #pragma unroll
        for (int i = 0; i < 8; ++i)
            #pragma unroll
            for (int j = 0; j < 4; ++j) acc[i][j] = 0.f;

        for (int k = 0; k < RAD; ++k) {
            const float4 wv = *(const float4*)(W1 + k * HID + c0);
            float l[8];
            #pragma unroll
            for (int i = 0; i < 8; ++i) l[i] = sLen[(eb + i) * RAD + k];
            #pragma unroll
            for (int i = 0; i < 8; ++i) {
                acc[i][0] += l[i] * wv.x;
                acc[i][1] += l[i] * wv.y;
                acc[i][2] += l[i] * wv.z;
                acc[i][3] += l[i] * wv.w;
            }
        }
        const float4 bv = *(const float4*)(b1 + c0);
        #pragma unroll
        for (int i = 0; i < 8; ++i) {
            sAct[(eb + i) * HID + c0 + 0] = acc[i][0] + bv.x;
            sAct[(eb + i) * HID + c0 + 1] = acc[i][1] + bv.y;
            sAct[(eb + i) * HID + c0 + 2] = acc[i][2] + bv.z;
            sAct[(eb + i) * HID + c0 + 3] = acc[i][3] + bv.w;
        }
    }
    __syncthreads();

    // ---------- Phase 3: LayerNorm + SiLU (in place) ----------
    {
        const int e = t >> 2;               // 0..63
        const int q = t & 3;                // 4 threads per edge, 32 cols each
        float s = 0.f, s2 = 0.f;
        #pragma unroll
        for (int c = 0; c < 32; ++c) {
            const float v = sAct[e * HID + q * 32 + c];
            s += v; s2 += v * v;
        }
        s  += __shfl_xor(s, 1);  s  += __shfl_xor(s, 2);
        s2 += __shfl_xor(s2, 1); s2 += __shfl_xor(s2, 2);
        const float mu  = s * (1.0f / HID);
        const float var = s2 * (1.0f / HID) - mu * mu;
        const float inv = rsqrtf(var + 1e-5f);
        #pragma unroll
        for (int c = 0; c < 32; ++c) {
            const int cc = q * 32 + c;
            const float v  = sAct[e * HID + cc];
            const float hn = (v - mu) * inv * g[cc] + be[cc];
            const float sl = hn / (1.0f + __expf(-hn));
            sAct[e * HID + cc] = sl;
        }
    }
    __syncthreads();

    // ---------- Phase 4: w = silu @ W2, fused DTP epilogue ----------
    {
        const int u  = t & 63;              // 0..63 (one u per thread)
        const int eb = (t >> 6) * 16;       // 16 edges per thread
        float acc[16][4];
        #pragma unroll
        for (int i = 0; i < 16; ++i)
            #pragma unroll
            for (int j = 0; j < 4; ++j) acc[i][j] = 0.f;

        for (int k = 0; k < HID; ++k) {
            float a[16];
            #pragma unroll
            for (int i = 0; i < 16; ++i) a[i] = sAct[(eb + i) * HID + k];
            const float w1v = W2[k * WN + 0   + u];
            const float w2v = W2[k * WN + 64  + u];
            const float w3v = W2[k * WN + 128 + u];
            const float w4v = W2[k * WN + 192 + u];
            #pragma unroll
            for (int i = 0; i < 16; ++i) {
                acc[i][0] += a[i] * w1v;
                acc[i][1] += a[i] * w2v;
                acc[i][2] += a[i] * w3v;
                acc[i][3] += a[i] * w4v;
            }
        }

        const float inv_s3 = 0.57735026918962576f;  // 1/sqrt(3)
        const float inv_s2 = 0.70710678118654752f;  // 1/sqrt(2)
        #pragma unroll 4
        for (int i = 0; i < 16; ++i) {
            const long e = e0 + eb + i;
            const float4 y = *(const float4*)(vec + e * 4);
            const float x0  = fea[e * FEA + u];
            const float x1a = fea[e * FEA + 64 + 3 * u + 0];
            const float x1b = fea[e * FEA + 64 + 3 * u + 1];
            const float x1c = fea[e * FEA + 64 + 3 * u + 2];
            const float w1c = acc[i][0], w2c = acc[i][1];
            const float w3c = acc[i][2], w4c = acc[i][3];
            const float dot = x1a * y.y + x1b * y.z + x1c * y.w;
            const float o0  = (w1c * x0 * y.x + w4c * dot * inv_s3) * inv_s2;
            const float o1a = (w2c * x0 * y.y + w3c * x1a * y.x) * inv_s2;
            const float o1b = (w2c * x0 * y.z + w3c * x1b * y.x) * inv_s2;
            const float o1c = (w2c * x0 * y.w + w3c * x1c * y.x) * inv_s2;
            outp[e * FEA + u]             = o0;
            outp[e * FEA + 64 + 3 * u + 0] = o1a;
            outp[e * FEA + 64 + 3 * u + 1] = o1b;
            outp[e * FEA + 64 + 3 * u + 2] = o1c;
        }
    }
}

extern "C" void kernel_launch(void* const* d_in, const int* in_sizes, int n_in,
                              void* d_out, int out_size, void* d_ws, size_t ws_size,
                              hipStream_t stream) {
    (void)in_sizes; (void)n_in; (void)d_ws; (void)ws_size; (void)out_size;
    const float* fea_a = (const float*)d_in[0];
    const float* vec_a = (const float*)d_in[1];
    const float* len_a = (const float*)d_in[2];
    const float* W1_a  = (const float*)d_in[3];
    const float* b1_a  = (const float*)d_in[4];
    const float* g_a   = (const float*)d_in[5];
    const float* be_a  = (const float*)d_in[6];
    const float* W2_a  = (const float*)d_in[7];
    const float* fea_b = (const float*)d_in[8];
    const float* vec_b = (const float*)d_in[9];
    const float* len_b = (const float*)d_in[10];
    const float* W1_b  = (const float*)d_in[11];
    const float* b1_b  = (const float*)d_in[12];
    const float* g_b   = (const float*)d_in[13];
    const float* be_b  = (const float*)d_in[14];
    const float* W2_b  = (const float*)d_in[15];
    float* out = (float*)d_out;

    dim3 grid(E_N / EPB, 2);
    dim3 block(NT);
    hipLaunchKernelGGL(fused_mlp_dtp, grid, block, 0, stream,
                       fea_a, vec_a, len_a, W1_a, b1_a, g_a, be_a, W2_a,
                       fea_b, vec_b, len_b, W1_b, b1_b, g_b, be_b, W2_b,
                       out);
}